// Round 4
// baseline (21.370 us; speedup 1.0000x reference)
//
#include <hip/hip_runtime.h>

// BackprojectDepth: out[b, 0:3, k] = depth[b, idx] * (inv_K[b,:3,:3] @ [gx, gy, 1])
//                   out[b, 3, k]   = 1.0
// idx = top_k_indices[b,k], gx = idx % W, gy = idx / W.
// pix_coords input is a meshgrid -> recomputed arithmetically, never read.
//
// Round 4 changes (on top of XCD remap + nontemporal stores):
//  - ILP=8: each thread handles 8 consecutive k (2x int4 idx loads, 8 independent
//    gathers in flight) -> more MLP per wave to cover L2/HBM gather latency.
//    1024 blocks x 256 threads, 64 blocks/batch, still 2 batches per XCD
//    (3.75MB depth working set < 4MB L2).

#define BB 16
#define HH 384
#define WW 1280
#define HWSZ (HH * WW)
#define KK 131072
#define NXCD 8
#define ELEMS 8
#define BLOCKS_PER_BATCH (KK / (256 * ELEMS))  // 64
#define TOTAL_BLOCKS (BB * BLOCKS_PER_BATCH)   // 1024

typedef float v4f __attribute__((ext_vector_type(4)));
typedef int   v4i __attribute__((ext_vector_type(4)));

__global__ __launch_bounds__(256) void backproject_kernel(
    const float* __restrict__ depth,   // B*HW
    const float* __restrict__ invK,    // B*16
    const int*   __restrict__ topk,    // B*K
    float*       __restrict__ out)     // B*4*K
{
    // Physical block i lands on XCD i%NXCD. Give XCD x a contiguous logical range.
    const int xcd  = blockIdx.x & (NXCD - 1);
    const int slot = blockIdx.x >> 3;                       // 0..127
    const int logical = xcd * (TOTAL_BLOCKS / NXCD) + slot; // 0..1023
    const int b   = logical >> 6;                           // /64 -> batch (2 per XCD)
    const int blk = logical & 63;                           // block within batch
    const int k0  = blk * (256 * ELEMS) + threadIdx.x * ELEMS;

    // 3x3 of inv_K for this batch (scalar address -> s_load broadcast)
    const float* __restrict__ M = invK + b * 16;
    const float m00 = M[0], m01 = M[1], m02 = M[2];
    const float m10 = M[4], m11 = M[5], m12 = M[6];
    const float m20 = M[8], m21 = M[9], m22 = M[10];

    const int* tb = topk + b * KK + k0;
    const v4i idxA = __builtin_nontemporal_load(reinterpret_cast<const v4i*>(tb));
    const v4i idxB = __builtin_nontemporal_load(reinterpret_cast<const v4i*>(tb + 4));
    const float* __restrict__ db = depth + b * HWSZ;

    int idxs[ELEMS];
    idxs[0] = idxA[0]; idxs[1] = idxA[1]; idxs[2] = idxA[2]; idxs[3] = idxA[3];
    idxs[4] = idxB[0]; idxs[5] = idxB[1]; idxs[6] = idxB[2]; idxs[7] = idxB[3];

    // issue all 8 gathers first (independent -> 8 loads in flight)
    float d[ELEMS];
#pragma unroll
    for (int j = 0; j < ELEMS; ++j) d[j] = db[idxs[j]];

    float ox[ELEMS], oy[ELEMS], oz[ELEMS];
#pragma unroll
    for (int j = 0; j < ELEMS; ++j) {
        const int idx = idxs[j];
        const float gx = (float)(idx % WW);
        const float gy = (float)(idx / WW);
        const float c0 = fmaf(m00, gx, fmaf(m01, gy, m02));
        const float c1 = fmaf(m10, gx, fmaf(m11, gy, m12));
        const float c2 = fmaf(m20, gx, fmaf(m21, gy, m22));
        ox[j] = d[j] * c0;
        oy[j] = d[j] * c1;
        oz[j] = d[j] * c2;
    }

    float* __restrict__ ob = out + (size_t)b * 4 * KK + k0;
    v4f vx0 = {ox[0], ox[1], ox[2], ox[3]}, vx1 = {ox[4], ox[5], ox[6], ox[7]};
    v4f vy0 = {oy[0], oy[1], oy[2], oy[3]}, vy1 = {oy[4], oy[5], oy[6], oy[7]};
    v4f vz0 = {oz[0], oz[1], oz[2], oz[3]}, vz1 = {oz[4], oz[5], oz[6], oz[7]};
    v4f vw  = {1.f, 1.f, 1.f, 1.f};
    __builtin_nontemporal_store(vx0, reinterpret_cast<v4f*>(ob + 0 * KK));
    __builtin_nontemporal_store(vx1, reinterpret_cast<v4f*>(ob + 0 * KK + 4));
    __builtin_nontemporal_store(vy0, reinterpret_cast<v4f*>(ob + 1 * KK));
    __builtin_nontemporal_store(vy1, reinterpret_cast<v4f*>(ob + 1 * KK + 4));
    __builtin_nontemporal_store(vz0, reinterpret_cast<v4f*>(ob + 2 * KK));
    __builtin_nontemporal_store(vz1, reinterpret_cast<v4f*>(ob + 2 * KK + 4));
    __builtin_nontemporal_store(vw,  reinterpret_cast<v4f*>(ob + 3 * KK));
    __builtin_nontemporal_store(vw,  reinterpret_cast<v4f*>(ob + 3 * KK + 4));
}

extern "C" void kernel_launch(void* const* d_in, const int* in_sizes, int n_in,
                              void* d_out, int out_size, void* d_ws, size_t ws_size,
                              hipStream_t stream) {
    const float* depth = (const float*)d_in[0];     // (B,1,H,W) f32
    const float* invK  = (const float*)d_in[1];     // (B,4,4) f32
    // d_in[2] = pix_coords — intentionally unused (recomputed from index)
    const int*   topk  = (const int*)d_in[3];       // (B,K) i32
    float* out = (float*)d_out;                     // (B,4,K) f32

    backproject_kernel<<<TOTAL_BLOCKS, 256, 0, stream>>>(depth, invK, topk, out);
}

// Round 5
// 21.360 us; speedup vs baseline: 1.0005x; 1.0005x over previous
//
#include <hip/hip_runtime.h>

// BackprojectDepth: out[b, 0:3, k] = depth[b, idx] * (inv_K[b,:3,:3] @ [gx, gy, 1])
//                   out[b, 3, k]   = 1.0
// idx = top_k_indices[b,k], gx = idx % W, gy = idx / W.
// pix_coords input is a meshgrid -> recomputed arithmetically, never read.
//
// Round 5: temporal batch phasing via grid oversubscription.
//  - 4096 blocks x 256 thr, ILP=2. Only ~2048 blocks resident at once; remap so
//    each XCD's first 256 dispatch slots are batch 2x, last 256 are batch 2x+1.
//    -> instantaneous per-XCD depth working set ~1.875MB (< 4MB L2, with room
//    for streams), vs 3.75MB when both batches run concurrently (R2/R3 config).
//  - Keeps 32 waves/CU resident throughout (R3 showed TLP loss is fatal).
//  - nt stores (streaming out must not evict depth), nt idx loads.

#define BB 16
#define HH 384
#define WW 1280
#define HWSZ (HH * WW)
#define KK 131072
#define NXCD 8
#define ELEMS 2
#define BLOCKS_PER_BATCH (KK / (256 * ELEMS))  // 256
#define TOTAL_BLOCKS (BB * BLOCKS_PER_BATCH)   // 4096
#define SLOTS_PER_XCD (TOTAL_BLOCKS / NXCD)    // 512

typedef float v2f __attribute__((ext_vector_type(2)));
typedef int   v2i __attribute__((ext_vector_type(2)));

__global__ __launch_bounds__(256) void backproject_kernel(
    const float* __restrict__ depth,   // B*HW
    const float* __restrict__ invK,    // B*16
    const int*   __restrict__ topk,    // B*K
    float*       __restrict__ out)     // B*4*K
{
    // Phys block i -> XCD i%8, slot i>>3 (0..511). Slots 0..255 -> batch 2x
    // (dispatched/resident first), slots 256..511 -> batch 2x+1 (backfilled
    // as early blocks retire) -> temporal phasing of the two batches.
    const int xcd  = blockIdx.x & (NXCD - 1);
    const int slot = blockIdx.x >> 3;                 // 0..511
    const int b    = 2 * xcd + (slot >> 8);           // batch
    const int blk  = slot & 255;                      // block within batch
    const int k0   = blk * (256 * ELEMS) + threadIdx.x * ELEMS;

    // 3x3 of inv_K for this batch (uniform address -> scalar broadcast)
    const float* __restrict__ M = invK + b * 16;
    const float m00 = M[0], m01 = M[1], m02 = M[2];
    const float m10 = M[4], m11 = M[5], m12 = M[6];
    const float m20 = M[8], m21 = M[9], m22 = M[10];

    const v2i idx2 = __builtin_nontemporal_load(
        reinterpret_cast<const v2i*>(topk + b * KK + k0));
    const float* __restrict__ db = depth + b * HWSZ;

    // issue both gathers first (independent, in flight together)
    const int i0 = idx2[0], i1 = idx2[1];
    const float d0 = db[i0];
    const float d1 = db[i1];

    const float gx0 = (float)(i0 % WW), gy0 = (float)(i0 / WW);
    const float gx1 = (float)(i1 % WW), gy1 = (float)(i1 / WW);

    const float x0 = d0 * fmaf(m00, gx0, fmaf(m01, gy0, m02));
    const float y0 = d0 * fmaf(m10, gx0, fmaf(m11, gy0, m12));
    const float z0 = d0 * fmaf(m20, gx0, fmaf(m21, gy0, m22));
    const float x1 = d1 * fmaf(m00, gx1, fmaf(m01, gy1, m02));
    const float y1 = d1 * fmaf(m10, gx1, fmaf(m11, gy1, m12));
    const float z1 = d1 * fmaf(m20, gx1, fmaf(m21, gy1, m22));

    float* __restrict__ ob = out + (size_t)b * 4 * KK + k0;
    v2f vx = {x0, x1}, vy = {y0, y1}, vz = {z0, z1}, vw = {1.f, 1.f};
    __builtin_nontemporal_store(vx, reinterpret_cast<v2f*>(ob + 0 * KK));
    __builtin_nontemporal_store(vy, reinterpret_cast<v2f*>(ob + 1 * KK));
    __builtin_nontemporal_store(vz, reinterpret_cast<v2f*>(ob + 2 * KK));
    __builtin_nontemporal_store(vw, reinterpret_cast<v2f*>(ob + 3 * KK));
}

extern "C" void kernel_launch(void* const* d_in, const int* in_sizes, int n_in,
                              void* d_out, int out_size, void* d_ws, size_t ws_size,
                              hipStream_t stream) {
    const float* depth = (const float*)d_in[0];     // (B,1,H,W) f32
    const float* invK  = (const float*)d_in[1];     // (B,4,4) f32
    // d_in[2] = pix_coords — intentionally unused (recomputed from index)
    const int*   topk  = (const int*)d_in[3];       // (B,K) i32
    float* out = (float*)d_out;                     // (B,4,K) f32

    backproject_kernel<<<TOTAL_BLOCKS, 256, 0, stream>>>(depth, invK, topk, out);
}